// Round 1
// baseline (184.375 us; speedup 1.0000x reference)
//
#include <hip/hip_runtime.h>
#include <math.h>

#define NB 4096
#define NA 8
#define BN (NB*NA)   // 32768

__device__ __forceinline__ float fast_tanh(float x){
    float e = __expf(2.0f*x);
    return 1.0f - 2.0f*__builtin_amdgcn_rcpf(e+1.0f);
}

// K0: M[e][f] = sum_d qw[e][d]*kw[f][d]; u[f] = sum_d qb[d]*kw[f][d]
__global__ __launch_bounds__(128) void k0_pre(const float* __restrict__ qw,
        const float* __restrict__ kw, const float* __restrict__ qb,
        float* __restrict__ M, float* __restrict__ u){
    int f = threadIdx.x;
    int e = blockIdx.x;
    if (e < 128){
        float acc = 0.f;
        for (int d=0; d<128; ++d) acc += qw[e*128+d]*kw[f*128+d];
        M[e*128+f] = acc;
    } else {
        float acc = 0.f;
        for (int d=0; d<128; ++d) acc += qb[d]*kw[f*128+d];
        u[f] = acc;
    }
}

// K1: conv encoder -> states[BN][48]  (cols: 0..31 conv2, 32..33 pos, 34..41 onehot, 42..47 zero)
__global__ __launch_bounds__(256) void k1_conv(const float* __restrict__ xin,
        const float* __restrict__ pos, const float* __restrict__ oneh,
        const float* __restrict__ w1, const float* __restrict__ b1,
        const float* __restrict__ w2, const float* __restrict__ b2,
        float* __restrict__ states){
    __shared__ float s_in[16*76];
    __shared__ float s_w1[432];
    __shared__ float s_b1[16];
    __shared__ float s_w2[4608];
    __shared__ float s_b2[32];
    __shared__ float s_h1[16*144];
    const int t = threadIdx.x;
    const int g0 = blockIdx.x*16;
    for (int u = t; u < 432; u += 256) s_w1[u] = w1[u];
    if (t < 16) s_b1[t] = b1[t];
    for (int u = t; u < 4608; u += 256) s_w2[u] = w2[u];
    if (t < 32) s_b2[t] = b2[t];
    for (int u = t; u < 1200; u += 256){
        int ag = u/75, r = u - ag*75;
        s_in[ag*76 + r] = xin[(size_t)g0*75 + u];
    }
    __syncthreads();
    // conv1: 16 agents x 16 oc x 9 positions
    for (int u = t; u < 2304; u += 256){
        int p9 = u % 9;
        int tmp = u / 9;
        int oc = tmp & 15;
        int ag = tmp >> 4;
        int y = p9 / 3, x = p9 - y*3;
        float acc = s_b1[oc];
        const float* wp = &s_w1[oc*27];
        const float* ip = &s_in[ag*76];
        #pragma unroll
        for (int ic=0; ic<3; ++ic)
          #pragma unroll
          for (int ky=0; ky<3; ++ky)
            #pragma unroll
            for (int kx=0; kx<3; ++kx)
                acc += ip[ic*25 + (y+ky)*5 + (x+kx)] * wp[ic*9 + ky*3 + kx];
        s_h1[ag*144 + oc*9 + p9] = (acc >= 0.f) ? acc : 0.01f*acc;
    }
    __syncthreads();
    // conv2: 16 agents x 32 oc (1x1 output)
    for (int u = t; u < 512; u += 256){
        int oc = u & 31;
        int ag = u >> 5;
        float acc = s_b2[oc];
        const float* wp = &s_w2[oc*144];
        const float* hp = &s_h1[ag*144];
        #pragma unroll 16
        for (int k=0; k<144; ++k) acc += hp[k]*wp[k];
        acc = (acc >= 0.f) ? acc : 0.01f*acc;
        states[(size_t)(g0+ag)*48 + oc] = acc;
    }
    for (int u = t; u < 256; u += 256){
        int ag = u >> 4, k = u & 15;
        float v = 0.f;
        if (k < 2) v = pos[(size_t)(g0+ag)*2 + k];
        else if (k < 10) v = oneh[(size_t)(g0+ag)*8 + (k-2)];
        states[(size_t)(g0+ag)*48 + 32 + k] = v;
    }
}

// K2: E = tanh(states @ se_w + se_b)   [BN][128]
__global__ __launch_bounds__(256) void k2_embed(const float* __restrict__ states,
        const float* __restrict__ se_w, const float* __restrict__ se_b,
        float* __restrict__ E){
    __shared__ float s_st[64*48];
    const int t = threadIdx.x;
    const int r0 = blockIdx.x*64;
    for (int u = t; u < 768; u += 256){
        int row = u/12, c4 = (u - row*12)*4;
        *(float4*)&s_st[row*48 + c4] = *(const float4*)&states[(size_t)(r0+row)*48 + c4];
    }
    __syncthreads();
    const int c4 = (t & 31)*4;
    const int rb = t >> 5;
    float4 acc[8];
    #pragma unroll
    for (int i=0;i<8;++i) acc[i] = make_float4(0.f,0.f,0.f,0.f);
    for (int k=0;k<42;++k){
        float4 w = *(const float4*)&se_w[k*128 + c4];
        #pragma unroll
        for (int i=0;i<8;++i){
            float s = s_st[(rb+8*i)*48 + k];
            acc[i].x += s*w.x; acc[i].y += s*w.y; acc[i].z += s*w.z; acc[i].w += s*w.w;
        }
    }
    float4 b = *(const float4*)&se_b[c4];
    #pragma unroll
    for (int i=0;i<8;++i){
        float4 o;
        o.x = fast_tanh(acc[i].x + b.x);
        o.y = fast_tanh(acc[i].y + b.y);
        o.z = fast_tanh(acc[i].z + b.z);
        o.w = fast_tanh(acc[i].w + b.w);
        *(float4*)&E[(size_t)(r0+rb+8*i)*128 + c4] = o;
    }
}

// K3: T = E @ M + u   [BN][128]
__global__ __launch_bounds__(256) void k3_T(const float* __restrict__ E,
        const float* __restrict__ M, const float* __restrict__ u,
        float* __restrict__ T){
    __shared__ float s_E[64*128];
    const int t = threadIdx.x;
    const int r0 = blockIdx.x*64;
    for (int q = t; q < 2048; q += 256){
        int row = q >> 5, c4 = (q & 31)*4;
        *(float4*)&s_E[row*128 + c4] = *(const float4*)&E[(size_t)(r0+row)*128 + c4];
    }
    __syncthreads();
    const int c4 = (t & 31)*4;
    const int rb = t >> 5;
    float4 acc[8];
    #pragma unroll
    for (int i=0;i<8;++i) acc[i] = make_float4(0.f,0.f,0.f,0.f);
    for (int k=0;k<128;++k){
        float4 w = *(const float4*)&M[k*128 + c4];
        #pragma unroll
        for (int i=0;i<8;++i){
            float s = s_E[(rb+8*i)*128 + k];
            acc[i].x += s*w.x; acc[i].y += s*w.y; acc[i].z += s*w.z; acc[i].w += s*w.w;
        }
    }
    float4 uu = *(const float4*)&u[c4];
    #pragma unroll
    for (int i=0;i<8;++i){
        float4 o;
        o.x = acc[i].x + uu.x; o.y = acc[i].y + uu.y;
        o.z = acc[i].z + uu.z; o.w = acc[i].w + uu.w;
        *(float4*)&T[(size_t)(r0+rb+8*i)*128 + c4] = o;
    }
}

// K4: weight[b][a][j] = softmax_j( (T_a . E_j)/sqrt(128) )
__global__ __launch_bounds__(256) void k4_attn(const float* __restrict__ T,
        const float* __restrict__ E, float* __restrict__ wout){
    __shared__ float sT[32*132];
    __shared__ float sE[32*132];
    const int t = threadIdx.x;
    const int r0 = blockIdx.x*32;   // 4 batches per block
    for (int q = t; q < 4096; q += 256){
        int row = q >> 7, col = q & 127;
        sT[row*132 + col] = T[(size_t)(r0+row)*128 + col];
        sE[row*132 + col] = E[(size_t)(r0+row)*128 + col];
    }
    __syncthreads();
    const int bq = t >> 6;
    const int a  = (t >> 3) & 7;
    const int j  = t & 7;
    const float* tp = &sT[(bq*8 + a)*132];
    const float* ep = &sE[(bq*8 + j)*132];
    float acc = 0.f;
    for (int k=0;k<128;++k) acc += tp[k]*ep[k];
    float s = acc * 0.08838834764831845f;  // 1/sqrt(128)
    float m = s;
    for (int off=1; off<8; off<<=1) m = fmaxf(m, __shfl_xor(m, off));
    float ex = __expf(s - m);
    float sum = ex;
    for (int off=1; off<8; off<<=1) sum += __shfl_xor(sum, off);
    wout[(size_t)(blockIdx.x*4 + bq)*64 + a*8 + j] = ex / sum;
}

// K5: SAPa = tanh(states@sapW[:42] + act@sapW[42:] + b), SAPp likewise with policies
__global__ __launch_bounds__(256) void k5_sap(const float* __restrict__ states,
        const float* __restrict__ acts, const float* __restrict__ pols,
        const float* __restrict__ sap_w, const float* __restrict__ sap_b,
        float* __restrict__ SAPa, float* __restrict__ SAPp){
    __shared__ float s_st[64*48];
    __shared__ float s_ac[64*5];
    __shared__ float s_po[64*5];
    const int t = threadIdx.x;
    const int r0 = blockIdx.x*64;
    for (int q = t; q < 768; q += 256){
        int row = q/12, c4 = (q - row*12)*4;
        *(float4*)&s_st[row*48 + c4] = *(const float4*)&states[(size_t)(r0+row)*48 + c4];
    }
    for (int q = t; q < 320; q += 256){
        s_ac[q] = acts[(size_t)r0*5 + q];
        s_po[q] = pols[(size_t)r0*5 + q];
    }
    __syncthreads();
    const int c4 = (t & 31)*4;
    const int rb = t >> 5;
    float4 acc[8];
    #pragma unroll
    for (int i=0;i<8;++i) acc[i] = make_float4(0.f,0.f,0.f,0.f);
    for (int k=0;k<42;++k){
        float4 w = *(const float4*)&sap_w[k*128 + c4];
        #pragma unroll
        for (int i=0;i<8;++i){
            float s = s_st[(rb+8*i)*48 + k];
            acc[i].x += s*w.x; acc[i].y += s*w.y; acc[i].z += s*w.z; acc[i].w += s*w.w;
        }
    }
    float4 wa[5];
    #pragma unroll
    for (int k=0;k<5;++k) wa[k] = *(const float4*)&sap_w[(42+k)*128 + c4];
    float4 b = *(const float4*)&sap_b[c4];
    #pragma unroll
    for (int i=0;i<8;++i){
        int r = rb + 8*i;
        float4 va = acc[i], vp = acc[i];
        #pragma unroll
        for (int k=0;k<5;++k){
            float av = s_ac[r*5+k], pv = s_po[r*5+k];
            va.x += av*wa[k].x; va.y += av*wa[k].y; va.z += av*wa[k].z; va.w += av*wa[k].w;
            vp.x += pv*wa[k].x; vp.y += pv*wa[k].y; vp.z += pv*wa[k].z; vp.w += pv*wa[k].w;
        }
        float4 oa, op;
        oa.x = fast_tanh(va.x + b.x); oa.y = fast_tanh(va.y + b.y);
        oa.z = fast_tanh(va.z + b.z); oa.w = fast_tanh(va.w + b.w);
        op.x = fast_tanh(vp.x + b.x); op.y = fast_tanh(vp.y + b.y);
        op.z = fast_tanh(vp.z + b.z); op.w = fast_tanh(vp.w + b.w);
        *(float4*)&SAPa[(size_t)(r0+r)*128 + c4] = oa;
        *(float4*)&SAPp[(size_t)(r0+r)*128 + c4] = op;
    }
}

// K6: AV = tanh(SAP@av_w + av_b); then A64 = AV@f1_w (no bias). For both variants.
__global__ __launch_bounds__(256) void k6_av(const float* __restrict__ SAPa,
        const float* __restrict__ SAPp,
        const float* __restrict__ av_w, const float* __restrict__ av_b,
        const float* __restrict__ f1_w,
        float* __restrict__ A64, float* __restrict__ P64){
    __shared__ float s_sap[64*128];
    __shared__ float s_av[64*128];
    const int t = threadIdx.x;
    const int r0 = blockIdx.x*64;
    for (int v=0; v<2; ++v){
        const float* src = v ? SAPp : SAPa;
        float* dst = v ? P64 : A64;
        for (int q = t; q < 2048; q += 256){
            int row = q >> 5, c4 = (q & 31)*4;
            *(float4*)&s_sap[row*128 + c4] = *(const float4*)&src[(size_t)(r0+row)*128 + c4];
        }
        __syncthreads();
        {
            const int c4 = (t & 31)*4;
            const int rb = t >> 5;
            float4 acc[8];
            #pragma unroll
            for (int i=0;i<8;++i) acc[i] = make_float4(0.f,0.f,0.f,0.f);
            for (int k=0;k<128;++k){
                float4 w = *(const float4*)&av_w[k*128 + c4];
                #pragma unroll
                for (int i=0;i<8;++i){
                    float s = s_sap[(rb+8*i)*128 + k];
                    acc[i].x += s*w.x; acc[i].y += s*w.y; acc[i].z += s*w.z; acc[i].w += s*w.w;
                }
            }
            float4 b = *(const float4*)&av_b[c4];
            #pragma unroll
            for (int i=0;i<8;++i){
                float4 o;
                o.x = fast_tanh(acc[i].x + b.x); o.y = fast_tanh(acc[i].y + b.y);
                o.z = fast_tanh(acc[i].z + b.z); o.w = fast_tanh(acc[i].w + b.w);
                *(float4*)&s_av[(rb+8*i)*128 + c4] = o;
            }
        }
        __syncthreads();
        {
            const int c4 = (t & 15)*4;
            const int rb = t >> 4;
            float4 acc[4];
            #pragma unroll
            for (int i=0;i<4;++i) acc[i] = make_float4(0.f,0.f,0.f,0.f);
            for (int k=0;k<128;++k){
                float4 w = *(const float4*)&f1_w[k*64 + c4];
                #pragma unroll
                for (int i=0;i<4;++i){
                    float s = s_av[(rb+16*i)*128 + k];
                    acc[i].x += s*w.x; acc[i].y += s*w.y; acc[i].z += s*w.z; acc[i].w += s*w.w;
                }
            }
            #pragma unroll
            for (int i=0;i<4;++i)
                *(float4*)&dst[(size_t)(r0+rb+16*i)*64 + c4] = acc[i];
        }
        __syncthreads();
    }
}

// K7: value[b][a][i] = f2_b + sum_c tanh(base64[a][c] + w[a][i]*(P64[i][c]-A64[i][c]) + f1_b[c]) * f2_w[c]
//     base64[a][c] = sum_j w[a][j]*A64[j][c]
__global__ __launch_bounds__(256) void k7_final(const float* __restrict__ A64,
        const float* __restrict__ P64, const float* __restrict__ wgt,
        const float* __restrict__ f1_b, const float* __restrict__ f2_w,
        const float* __restrict__ f2_b, float* __restrict__ value){
    __shared__ float sA[2048];
    __shared__ float sP[2048];
    __shared__ float sw[256];
    __shared__ float sb64[2048];
    const int t = threadIdx.x;
    const int b0 = blockIdx.x*4;
    for (int q = t; q < 2048; q += 256){
        sA[q] = A64[(size_t)b0*512 + q];
        sP[q] = P64[(size_t)b0*512 + q];
    }
    sw[t] = wgt[(size_t)b0*64 + t];
    __syncthreads();
    for (int q = t; q < 2048; q += 256){
        int bq = q >> 9; int a = (q >> 6) & 7; int c = q & 63;
        float acc = 0.f;
        #pragma unroll
        for (int j=0;j<8;++j) acc += sw[bq*64 + a*8 + j] * sA[(bq*8+j)*64 + c];
        sb64[q] = acc;
    }
    __syncthreads();
    const int bq = t >> 6;
    const int a  = (t >> 3) & 7;
    const int i  = t & 7;
    const float w_ai = sw[bq*64 + a*8 + i];
    const float* pb = &sb64[(bq*8+a)*64];
    const float* pA = &sA[(bq*8+i)*64];
    const float* pP = &sP[(bq*8+i)*64];
    float acc = 0.f;
    for (int c=0;c<64;++c){
        float d = pP[c] - pA[c];
        float vv = fast_tanh(pb[c] + w_ai*d + f1_b[c]);
        acc += vv * f2_w[c];
    }
    value[(size_t)b0*64 + t] = acc + f2_b[0];
}

extern "C" void kernel_launch(void* const* d_in, const int* in_sizes, int n_in,
                              void* d_out, int out_size, void* d_ws, size_t ws_size,
                              hipStream_t stream){
    const float* agent_states = (const float*)d_in[0];
    const float* pos    = (const float*)d_in[1];
    const float* oneh   = (const float*)d_in[2];
    const float* pols   = (const float*)d_in[3];
    const float* acts   = (const float*)d_in[4];
    const float* w1     = (const float*)d_in[5];
    const float* b1     = (const float*)d_in[6];
    const float* w2     = (const float*)d_in[7];
    const float* b2     = (const float*)d_in[8];
    const float* se_w   = (const float*)d_in[9];
    const float* se_b   = (const float*)d_in[10];
    const float* key_w  = (const float*)d_in[11];
    const float* query_w= (const float*)d_in[13];
    const float* query_b= (const float*)d_in[14];
    const float* sap_w  = (const float*)d_in[15];
    const float* sap_b  = (const float*)d_in[16];
    const float* av_w   = (const float*)d_in[17];
    const float* av_b   = (const float*)d_in[18];
    const float* f1_w   = (const float*)d_in[19];
    const float* f1_b   = (const float*)d_in[20];
    const float* f2_w   = (const float*)d_in[21];
    const float* f2_b   = (const float*)d_in[22];

    float* ws = (float*)d_ws;
    float* M      = ws;                          // 16384
    float* u      = ws + 16384;                  // 128
    float* states = ws + 16512;                  // BN*48
    float* E      = states + (size_t)BN*48;      // BN*128
    float* T      = E + (size_t)BN*128;          // BN*128
    float* SAPa   = E;                           // reuse (E dead after k4)
    float* SAPp   = T;                           // reuse (T dead after k4)
    float* A64    = T + (size_t)BN*128;          // BN*64
    float* P64    = A64 + (size_t)BN*64;         // BN*64

    float* value = (float*)d_out;
    float* wout  = value + (size_t)NB*NA*NA;

    k0_pre <<<129, 128, 0, stream>>>(query_w, key_w, query_b, M, u);
    k1_conv<<<BN/16, 256, 0, stream>>>(agent_states, pos, oneh, w1, b1, w2, b2, states);
    k2_embed<<<BN/64, 256, 0, stream>>>(states, se_w, se_b, E);
    k3_T   <<<BN/64, 256, 0, stream>>>(E, M, u, T);
    k4_attn<<<BN/32, 256, 0, stream>>>(T, E, wout);
    k5_sap <<<BN/64, 256, 0, stream>>>(states, acts, pols, sap_w, sap_b, SAPa, SAPp);
    k6_av  <<<BN/64, 256, 0, stream>>>(SAPa, SAPp, av_w, av_b, f1_w, A64, P64);
    k7_final<<<NB/4, 256, 0, stream>>>(A64, P64, wout, f1_b, f2_w, f2_b, value);
}